// Round 1
// baseline (6700.121 us; speedup 1.0000x reference)
//
#include <hip/hip_runtime.h>
#include <cstddef>
#include <cstdint>

// ---------------------------------------------------------------------------
// GRU sequence model (flax GRUCell, gate_fn=silu, activation=tanh)
// T=512, B=128, F_IN=1030, H=512
//   xg = x @ Wi + bi                (big parallel GEMM, bf16 MFMA)
//   per step: r=silu(xr+h@Wr) z=silu(xz+h@Wz) n=tanh(xn+r*(h@Wn+bhn))
//             h' = (1-z)*n + z*h   (h carried in fp32; MFMA operands bf16)
// Output: [carry (B*H) | ys (T*B*H)] fp32
// ---------------------------------------------------------------------------

#define T_STEPS 512
#define BATCH   128
#define F_IN    1030
#define KPAD    1056          // 33 * 32
#define H       512
#define G3      1536          // 3*H
#define TCHUNK  64
#define MCHUNK  (TCHUNK * BATCH)   // 8192 rows per chunk

using f32x4  = __attribute__((ext_vector_type(4)))  float;
using bf16x8 = __attribute__((ext_vector_type(8)))  short;
using u16x8  = __attribute__((ext_vector_type(8)))  unsigned short;
using u16x4  = __attribute__((ext_vector_type(4)))  unsigned short;

__device__ __forceinline__ unsigned short f2bf(float f) {
    unsigned int u = __builtin_bit_cast(unsigned int, f);
    u = (u + 0x7FFFu + ((u >> 16) & 1u)) >> 16;   // round-to-nearest-even
    return (unsigned short)u;
}
__device__ __forceinline__ float bf2f(unsigned short s) {
    unsigned int u = ((unsigned int)s) << 16;
    return __builtin_bit_cast(float, u);
}

// ---------------------------------------------------------------------------
// Wi [F_IN][G3] fp32  ->  wiT [G3][KPAD] bf16 (transposed, zero-padded K)
// grid (KPAD/32=33, G3/32=48), block (32,8)
// ---------------------------------------------------------------------------
__global__ __launch_bounds__(256) void transpose_wi(const float* __restrict__ Wi,
                                                    unsigned short* __restrict__ wiT) {
    __shared__ float t_lds[32][33];
    const int kx = blockIdx.x, gy = blockIdx.y;
    const int tx = threadIdx.x, ty = threadIdx.y;
#pragma unroll
    for (int r = 0; r < 4; ++r) {
        int k = kx * 32 + ty + r * 8;
        int g = gy * 32 + tx;
        t_lds[ty + r * 8][tx] = (k < F_IN) ? Wi[(size_t)k * G3 + g] : 0.f;
    }
    __syncthreads();
#pragma unroll
    for (int r = 0; r < 4; ++r) {
        int g = gy * 32 + ty + r * 8;
        int k = kx * 32 + tx;
        wiT[(size_t)g * KPAD + k] = f2bf(t_lds[tx][ty + r * 8]);
    }
}

// ---------------------------------------------------------------------------
// Wh_rz [H][2H], Wh_n [H][H] fp32 -> whT [G3][H] bf16 column-major
// rows 0..511 = r cols, 512..1023 = z cols, 1024..1535 = n cols
// grid (H/32=16, G3/32=48), block (32,8)
// ---------------------------------------------------------------------------
__global__ __launch_bounds__(256) void transpose_wh(const float* __restrict__ Whrz,
                                                    const float* __restrict__ Whn,
                                                    unsigned short* __restrict__ whT) {
    __shared__ float t_lds[32][33];
    const int kx = blockIdx.x, cy = blockIdx.y;
    const int tx = threadIdx.x, ty = threadIdx.y;
#pragma unroll
    for (int r = 0; r < 4; ++r) {
        int k = kx * 32 + ty + r * 8;
        int c = cy * 32 + tx;
        float v = (c < 1024) ? Whrz[(size_t)k * 1024 + c]
                             : Whn[(size_t)k * H + (c - 1024)];
        t_lds[ty + r * 8][tx] = v;
    }
    __syncthreads();
#pragma unroll
    for (int r = 0; r < 4; ++r) {
        int c = cy * 32 + ty + r * 8;
        int k = kx * 32 + tx;
        whT[(size_t)c * H + k] = f2bf(t_lds[tx][ty + r * 8]);
    }
}

// ---------------------------------------------------------------------------
// xg chunk GEMM: [MCHUNK][F_IN] fp32 @ wiT -> xg [MCHUNK][G3] bf16 (+bi)
// 64x64 tile, BK=32, 256 thr (4 waves, each a 32x32 quadrant = 2x2 MFMA tiles)
// grid (G3/64=24, MCHUNK/64=128)
// ---------------------------------------------------------------------------
__global__ __launch_bounds__(256) void gemm_xg(const float* __restrict__ x,
                                               const unsigned short* __restrict__ wiT,
                                               const float* __restrict__ bi,
                                               unsigned short* __restrict__ xg) {
    __shared__ unsigned short a_lds[64][40];   // [row][k] bf16, pad 40
    __shared__ unsigned short b_lds[64][40];   // [col][k] bf16 (B^T), pad 40
    const int tid = threadIdx.x;
    const int n0 = blockIdx.x * 64;
    const int m0 = blockIdx.y * 64;
    const int l = tid & 63, w = tid >> 6;
    const int wr = w >> 1, wc = w & 1;
    const int si = tid >> 2;            // staging row/col 0..63
    const int sk = (tid & 3) * 8;       // staging k offset 0,8,16,24

    f32x4 acc[2][2] = {};

    for (int kt = 0; kt < 33; ++kt) {
        if (kt) __syncthreads();
        // stage A (fp32 -> bf16 on the fly, guard k < F_IN)
        {
            const int kb = kt * 32 + sk;
            const float* src = x + (size_t)(m0 + si) * F_IN + kb;
            u16x8 v;
#pragma unroll
            for (int e = 0; e < 8; ++e)
                v[e] = (kb + e < F_IN) ? f2bf(src[e]) : (unsigned short)0;
            *(u16x8*)&a_lds[si][sk] = v;
            // stage B^T from pre-transposed bf16 (no guard: padded)
            *(u16x8*)&b_lds[si][sk] =
                *(const u16x8*)(wiT + (size_t)(n0 + si) * KPAD + kt * 32 + sk);
        }
        __syncthreads();
        const int ka = (l >> 4) * 8;
        bf16x8 a0 = *(const bf16x8*)&a_lds[wr * 32 + (l & 15)][ka];
        bf16x8 a1 = *(const bf16x8*)&a_lds[wr * 32 + 16 + (l & 15)][ka];
        bf16x8 b0 = *(const bf16x8*)&b_lds[wc * 32 + (l & 15)][ka];
        bf16x8 b1 = *(const bf16x8*)&b_lds[wc * 32 + 16 + (l & 15)][ka];
        acc[0][0] = __builtin_amdgcn_mfma_f32_16x16x32_bf16(a0, b0, acc[0][0], 0, 0, 0);
        acc[0][1] = __builtin_amdgcn_mfma_f32_16x16x32_bf16(a0, b1, acc[0][1], 0, 0, 0);
        acc[1][0] = __builtin_amdgcn_mfma_f32_16x16x32_bf16(a1, b0, acc[1][0], 0, 0, 0);
        acc[1][1] = __builtin_amdgcn_mfma_f32_16x16x32_bf16(a1, b1, acc[1][1], 0, 0, 0);
    }

    // epilogue: C/D layout col = l&15, row = (l>>4)*4 + q   [m89-verified]
#pragma unroll
    for (int n = 0; n < 2; ++n) {
        const int col = n0 + wc * 32 + n * 16 + (l & 15);
        const float bv = bi[col];
#pragma unroll
        for (int m = 0; m < 2; ++m) {
#pragma unroll
            for (int q = 0; q < 4; ++q) {
                const int row = m0 + wr * 32 + m * 16 + (l >> 4) * 4 + q;
                xg[(size_t)row * G3 + col] = f2bf(acc[m][n][q] + bv);
            }
        }
    }
}

// ---------------------------------------------------------------------------
// One GRU step. grid (H/32=16 j-tiles, BATCH/16=8 b-tiles), block 128 (2 waves)
// Each wave: 16 output cols x 16 batch rows x 3 gates, K=512 (4 kt x 4 ki).
// h read fp32, rounded to bf16 for MFMA only; h' written fp32 to ys[t].
// ---------------------------------------------------------------------------
__global__ __launch_bounds__(128) void gru_step(const float* __restrict__ h_prev,   // [B][H]
                                                const unsigned short* __restrict__ xg, // chunk [TCHUNK*B][G3]
                                                int t_local,
                                                const unsigned short* __restrict__ whT, // [G3][H]
                                                const float* __restrict__ bhn,       // [H]
                                                float* __restrict__ ys_t,            // [B][H]
                                                float* __restrict__ carry) {         // or nullptr
    __shared__ unsigned short h_lds[16][520];       // [b_local][k] bf16
    __shared__ unsigned short w_lds[3][32][136];    // [gate][j_local][k-tile 128]
    const int tid = threadIdx.x;
    const int j0 = blockIdx.x * 32;
    const int b0 = blockIdx.y * 16;
    const int l = tid & 63, w = tid >> 6;

    // stage h: 16 rows x 512 cols, fp32 -> bf16
#pragma unroll
    for (int i = 0; i < 16; ++i) {
        int e = tid + i * 128;           // 0..2047
        int row = e >> 7;                // 0..15
        int k4 = (e & 127) * 4;          // 0..508
        const float4 hv = *(const float4*)&h_prev[(size_t)(b0 + row) * H + k4];
        u16x4 p;
        p[0] = f2bf(hv.x); p[1] = f2bf(hv.y); p[2] = f2bf(hv.z); p[3] = f2bf(hv.w);
        *(u16x4*)&h_lds[row][k4] = p;
    }

    f32x4 acc[3] = {};

    for (int kt = 0; kt < 4; ++kt) {
        __syncthreads();   // kt=0: h staged; kt>0: prior fragment reads done
        // stage W: 3 gates x 32 cols x 128 k  (1536 u16x8 loads, 12/thread)
#pragma unroll
        for (int i = 0; i < 12; ++i) {
            int L = tid + i * 128;       // 0..1535
            int g = L >> 9;              // 0..2
            int r = L & 511;
            int jc = r >> 4;             // 0..31
            int k8 = (r & 15) * 8;       // 0..120
            *(u16x8*)&w_lds[g][jc][k8] =
                *(const u16x8*)(whT + (size_t)(g * H + j0 + jc) * H + kt * 128 + k8);
        }
        __syncthreads();
#pragma unroll
        for (int ki = 0; ki < 4; ++ki) {
            const int ko = ki * 32 + (l >> 4) * 8;
            bf16x8 a = *(const bf16x8*)&h_lds[l & 15][kt * 128 + ko];
#pragma unroll
            for (int g = 0; g < 3; ++g) {
                bf16x8 b = *(const bf16x8*)&w_lds[g][w * 16 + (l & 15)][ko];
                acc[g] = __builtin_amdgcn_mfma_f32_16x16x32_bf16(a, b, acc[g], 0, 0, 0);
            }
        }
    }

    // epilogue: D col = l&15 -> j_local; D row = (l>>4)*4+q -> b_local
    const int j = j0 + w * 16 + (l & 15);
    const float bnv = bhn[j];
#pragma unroll
    for (int q = 0; q < 4; ++q) {
        const int b = b0 + (l >> 4) * 4 + q;
        const size_t rb = (size_t)(t_local * BATCH + b) * G3;
        float xr = bf2f(xg[rb + j]);
        float xz = bf2f(xg[rb + H + j]);
        float xn = bf2f(xg[rb + 2 * H + j]);
        float pr = xr + acc[0][q];
        float pz = xz + acc[1][q];
        float r = pr / (1.f + __expf(-pr));      // silu
        float z = pz / (1.f + __expf(-pz));
        float n = tanhf(xn + r * (acc[2][q] + bnv));
        float hv = h_prev[(size_t)b * H + j];
        float ho = (1.f - z) * n + z * hv;
        ys_t[(size_t)b * H + j] = ho;
        if (carry) carry[(size_t)b * H + j] = ho;
    }
}

// ---------------------------------------------------------------------------
extern "C" void kernel_launch(void* const* d_in, const int* in_sizes, int n_in,
                              void* d_out, int out_size, void* d_ws, size_t ws_size,
                              hipStream_t stream) {
    const float* h0   = (const float*)d_in[0];
    const float* x    = (const float*)d_in[1];
    const float* Wi   = (const float*)d_in[2];
    const float* bi   = (const float*)d_in[3];
    const float* Whrz = (const float*)d_in[4];
    const float* Whn  = (const float*)d_in[5];
    const float* bhn  = (const float*)d_in[6];

    float* carry = (float*)d_out;                       // [B][H]
    float* ys    = (float*)d_out + (size_t)BATCH * H;   // [T][B][H]

    // workspace layout (bf16): wiT [G3][KPAD] | whT [G3][H] | xg chunk [MCHUNK][G3]
    unsigned short* wiT = (unsigned short*)d_ws;
    unsigned short* whT = wiT + (size_t)G3 * KPAD;
    unsigned short* xg  = whT + (size_t)G3 * H;

    transpose_wi<<<dim3(KPAD / 32, G3 / 32), dim3(32, 8), 0, stream>>>(Wi, wiT);
    transpose_wh<<<dim3(H / 32, G3 / 32), dim3(32, 8), 0, stream>>>(Whrz, Whn, whT);

    for (int c = 0; c < T_STEPS / TCHUNK; ++c) {
        gemm_xg<<<dim3(G3 / 64, MCHUNK / 64), 256, 0, stream>>>(
            x + (size_t)c * MCHUNK * F_IN, wiT, bi, xg);
        for (int tl = 0; tl < TCHUNK; ++tl) {
            const int t = c * TCHUNK + tl;
            const float* hp = (t == 0) ? h0 : ys + (size_t)(t - 1) * BATCH * H;
            gru_step<<<dim3(H / 32, BATCH / 16), 128, 0, stream>>>(
                hp, xg, tl, whT, bhn,
                ys + (size_t)t * BATCH * H,
                (t == T_STEPS - 1) ? carry : nullptr);
        }
    }
}